// Round 7
// baseline (306.348 us; speedup 1.0000x reference)
//
#include <hip/hip_runtime.h>
#include <hip/hip_bf16.h>
#include <cstdint>

typedef __attribute__((ext_vector_type(8))) short short8;
typedef __attribute__((ext_vector_type(4))) float f32x4;
typedef __attribute__((ext_vector_type(2))) __fp16 pk16x2;     // cvt_pkrtz native type
typedef __attribute__((ext_vector_type(4))) _Float16 half4_;

#define B_  2
#define S_  2048
#define D_  1024
#define H_  16
#define HD  64

static __device__ __forceinline__ float bf2f(unsigned int u16) {
    union { unsigned int i; float f; } v; v.i = u16 << 16; return v.f;
}
static __device__ __forceinline__ unsigned short f2bf(float f) {
    union { float f; unsigned int i; } v; v.f = f;
    unsigned int r = v.i + 0x7FFFu + ((v.i >> 16) & 1u);
    return (unsigned short)(r >> 16);
}
static __device__ __forceinline__ unsigned pack_bf16(float hi, float lo) {
    union { float f; unsigned u; } h, l;
    h.f = hi; l.f = lo;
    return __builtin_amdgcn_perm(h.u + 0x8000u, l.u + 0x8000u, 0x07060302);
}
static __device__ __forceinline__ void load_lds_16B(const unsigned short* g, unsigned short* l) {
    __builtin_amdgcn_global_load_lds(
        (const __attribute__((address_space(1))) unsigned int*)g,
        (__attribute__((address_space(3))) unsigned int*)l, 16, 0, 0);
}

// ---------------- fp32 -> bf16 conversion, x + all 4 weights -------------
__global__ void cvt_all(const float* __restrict__ x,
                        const float* __restrict__ w0, const float* __restrict__ w1,
                        const float* __restrict__ w2, const float* __restrict__ w3,
                        unsigned short* __restrict__ xbf,
                        unsigned short* __restrict__ wdst) {
    int bid = blockIdx.x;
    if (bid < 4096) {
        int i = bid * 256 + threadIdx.x;
        float4 f = ((const float4*)x)[i];
        uint2 o;
        o.x = (unsigned int)f2bf(f.x) | ((unsigned int)f2bf(f.y) << 16);
        o.y = (unsigned int)f2bf(f.z) | ((unsigned int)f2bf(f.w) << 16);
        ((uint2*)xbf)[i] = o;
    } else {
        int b2 = bid - 4096;
        int wsel = b2 >> 10;
        const float* s = wsel == 0 ? w0 : wsel == 1 ? w1 : wsel == 2 ? w2 : w3;
        int i = (b2 & 1023) * 256 + threadIdx.x;
        float4 f = ((const float4*)s)[i];
        uint2 o;
        o.x = (unsigned int)f2bf(f.x) | ((unsigned int)f2bf(f.y) << 16);
        o.y = (unsigned int)f2bf(f.z) | ((unsigned int)f2bf(f.w) << 16);
        ((uint2*)(wdst + (size_t)wsel * 1048576))[i] = o;
    }
}

// ---------------- fused QKV GEMM, 128x128 tile, BK=64 --------------------
// q written [B,H,S,hd] bf16; k written [B,H,S,hd] bf16 WITH ROPE APPLIED;
// v written TRANSPOSED f16 to vt [B,H,hd,S].
__global__ __launch_bounds__(256) void qkv_gemm(
    const unsigned short* __restrict__ xbf,
    const unsigned short* __restrict__ wq,
    const unsigned short* __restrict__ wk,
    const unsigned short* __restrict__ wv,
    const float* __restrict__ fcos,
    const float* __restrict__ fsin,
    unsigned short* __restrict__ qb,
    unsigned short* __restrict__ kb,
    unsigned short* __restrict__ vt)
{
    __shared__ unsigned short As[2 * 8 * 512];   // [kh][rowblk][lane*8]
    __shared__ unsigned short Bs[2 * 8 * 512];
    __shared__ unsigned short LT[64 * 136];      // V transpose buffer

    const int tid  = threadIdx.x;
    const int w    = tid >> 6, lane = tid & 63;
    const int l15  = lane & 15, quad = lane >> 4;
    const int wrow = (w >> 1) * 64, wcol = (w & 1) * 64;

    const int m0 = blockIdx.x * 128;
    const int nc = blockIdx.y * 128;
    const int sel = nc >> 10;
    const int n0 = nc & 1023;
    const unsigned short* __restrict__ W = sel == 0 ? wq : (sel == 1 ? wk : wv);

    const int slr = lane & 15, scg = (lane >> 4) * 8;
    const unsigned short* ga = xbf + (size_t)(m0 + slr) * 1024 + scg;
    const unsigned short* gb = W   + (size_t)(n0 + slr) * 1024 + scg;

    f32x4 acc[4][4] = {};

    for (int k0 = 0; k0 < 1024; k0 += 64) {
        __syncthreads();
        load_lds_16B(ga + (size_t)(w * 16) * 1024 + k0,             As + (0 * 8 + w) * 512);
        load_lds_16B(ga + (size_t)(w * 16) * 1024 + k0 + 32,        As + (1 * 8 + w) * 512);
        load_lds_16B(ga + (size_t)(64 + w * 16) * 1024 + k0,        As + (0 * 8 + w + 4) * 512);
        load_lds_16B(ga + (size_t)(64 + w * 16) * 1024 + k0 + 32,   As + (1 * 8 + w + 4) * 512);
        load_lds_16B(gb + (size_t)(w * 16) * 1024 + k0,             Bs + (0 * 8 + w) * 512);
        load_lds_16B(gb + (size_t)(w * 16) * 1024 + k0 + 32,        Bs + (1 * 8 + w) * 512);
        load_lds_16B(gb + (size_t)(64 + w * 16) * 1024 + k0,        Bs + (0 * 8 + w + 4) * 512);
        load_lds_16B(gb + (size_t)(64 + w * 16) * 1024 + k0 + 32,   Bs + (1 * 8 + w + 4) * 512);
        __syncthreads();

#pragma unroll
        for (int kh = 0; kh < 2; kh++) {
            short8 a[4], b[4];
#pragma unroll
            for (int i = 0; i < 4; i++)
                a[i] = *(const short8*)&As[((kh * 8 + (w >> 1) * 4 + i) * 64 + lane) * 8];
#pragma unroll
            for (int j = 0; j < 4; j++)
                b[j] = *(const short8*)&Bs[((kh * 8 + (w & 1) * 4 + j) * 64 + lane) * 8];
#pragma unroll
            for (int i = 0; i < 4; i++)
#pragma unroll
                for (int j = 0; j < 4; j++)
                    acc[i][j] = __builtin_amdgcn_mfma_f32_16x16x32_bf16(a[i], b[j], acc[i][j], 0, 0, 0);
        }
    }

    if (sel == 0) {
        // Q: plain scatter to [B,H,S,hd]
#pragma unroll
        for (int i = 0; i < 4; i++)
#pragma unroll
            for (int r = 0; r < 4; r++) {
                int m = m0 + wrow + i * 16 + quad * 4 + r;
                int bb = m >> 11, s = m & 2047;
#pragma unroll
                for (int j = 0; j < 4; j++) {
                    int n = n0 + wcol + j * 16 + l15;
                    int h = n >> 6, d = n & 63;
                    qb[(((size_t)(bb * H_ + h) * S_) + s) * HD + d] = f2bf(acc[i][j][r]);
                }
            }
    } else if (sel == 1) {
        // K: fused RoPE (pair exchange via shfl_xor lane^1), then scatter
#pragma unroll
        for (int i = 0; i < 4; i++)
#pragma unroll
            for (int r = 0; r < 4; r++) {
                int m = m0 + wrow + i * 16 + quad * 4 + r;
                int bb = m >> 11, s = m & 2047;
#pragma unroll
                for (int j = 0; j < 4; j++) {
                    int n = n0 + wcol + j * 16 + l15;
                    int h = n >> 6, d = n & 63, t = d >> 1;
                    float v = acc[i][j][r];
                    float o = __shfl_xor(v, 1, 64);
                    float c  = fcos[s * 32 + t];
                    float si = fsin[s * 32 + t];
                    float outv = (l15 & 1) ? (v * c + o * si) : (v * c - o * si);
                    kb[(((size_t)(bb * H_ + h) * S_) + s) * HD + d] = f2bf(outv);
                }
            }
    } else {
        // V: transpose via LDS, write f16 to vt[B,H,hd,S]
        const int bb = m0 >> 11, s0 = m0 & 2047;
#pragma unroll
        for (int nh = 0; nh < 2; nh++) {
            __syncthreads();
            if ((w & 1) == nh) {
#pragma unroll
                for (int i = 0; i < 4; i++)
#pragma unroll
                    for (int r = 0; r < 4; r++) {
                        int ml = wrow + i * 16 + quad * 4 + r;
#pragma unroll
                        for (int j = 0; j < 4; j++) {
                            union { _Float16 h; unsigned short u; } cv;
                            cv.h = (_Float16)acc[i][j][r];
                            LT[(j * 16 + l15) * 136 + ml] = cv.u;
                        }
                    }
            }
            __syncthreads();
            int dloc = tid >> 2, mseg = tid & 3;
            int h = (n0 + nh * 64) >> 6;
            unsigned short* dst = vt + (((size_t)bb * H_ + h) * HD + dloc) * 2048 + s0 + mseg * 32;
            uint2 r0 = *(const uint2*)&LT[dloc * 136 + mseg * 32];
            uint2 r1 = *(const uint2*)&LT[dloc * 136 + mseg * 32 + 4];
            uint2 r2 = *(const uint2*)&LT[dloc * 136 + mseg * 32 + 8];
            uint2 r3 = *(const uint2*)&LT[dloc * 136 + mseg * 32 + 12];
            uint2 r4 = *(const uint2*)&LT[dloc * 136 + mseg * 32 + 16];
            uint2 r5 = *(const uint2*)&LT[dloc * 136 + mseg * 32 + 20];
            uint2 r6 = *(const uint2*)&LT[dloc * 136 + mseg * 32 + 24];
            uint2 r7 = *(const uint2*)&LT[dloc * 136 + mseg * 32 + 28];
            ((uint4*)dst)[0] = make_uint4(r0.x, r0.y, r1.x, r1.y);
            ((uint4*)dst)[1] = make_uint4(r2.x, r2.y, r3.x, r3.y);
            ((uint4*)dst)[2] = make_uint4(r4.x, r4.y, r5.x, r5.y);
            ((uint4*)dst)[3] = make_uint4(r6.x, r6.y, r7.x, r7.y);
        }
    }
}

// ---------------- output GEMM, BK=64 -------------------------------------
__global__ __launch_bounds__(256) void out_gemm(
    const unsigned short* __restrict__ A,
    const unsigned short* __restrict__ Bt,
    float* __restrict__ C)
{
    __shared__ unsigned short As[2 * 8 * 512];
    __shared__ unsigned short Bs[2 * 8 * 512];

    const int tid  = threadIdx.x;
    const int w    = tid >> 6, lane = tid & 63;
    const int l15  = lane & 15, quad = lane >> 4;
    const int wrow = (w >> 1) * 64, wcol = (w & 1) * 64;

    const int m0 = blockIdx.x * 128;
    const int n0 = blockIdx.y * 128;

    const int slr = lane & 15, scg = (lane >> 4) * 8;
    const unsigned short* ga = A  + (size_t)(m0 + slr) * 1024 + scg;
    const unsigned short* gb = Bt + (size_t)(n0 + slr) * 1024 + scg;

    f32x4 acc[4][4] = {};

    for (int k0 = 0; k0 < 1024; k0 += 64) {
        __syncthreads();
        load_lds_16B(ga + (size_t)(w * 16) * 1024 + k0,             As + (0 * 8 + w) * 512);
        load_lds_16B(ga + (size_t)(w * 16) * 1024 + k0 + 32,        As + (1 * 8 + w) * 512);
        load_lds_16B(ga + (size_t)(64 + w * 16) * 1024 + k0,        As + (0 * 8 + w + 4) * 512);
        load_lds_16B(ga + (size_t)(64 + w * 16) * 1024 + k0 + 32,   As + (1 * 8 + w + 4) * 512);
        load_lds_16B(gb + (size_t)(w * 16) * 1024 + k0,             Bs + (0 * 8 + w) * 512);
        load_lds_16B(gb + (size_t)(w * 16) * 1024 + k0 + 32,        Bs + (1 * 8 + w) * 512);
        load_lds_16B(gb + (size_t)(64 + w * 16) * 1024 + k0,        Bs + (0 * 8 + w + 4) * 512);
        load_lds_16B(gb + (size_t)(64 + w * 16) * 1024 + k0 + 32,   Bs + (1 * 8 + w + 4) * 512);
        __syncthreads();

#pragma unroll
        for (int kh = 0; kh < 2; kh++) {
            short8 a[4], b[4];
#pragma unroll
            for (int i = 0; i < 4; i++)
                a[i] = *(const short8*)&As[((kh * 8 + (w >> 1) * 4 + i) * 64 + lane) * 8];
#pragma unroll
            for (int j = 0; j < 4; j++)
                b[j] = *(const short8*)&Bs[((kh * 8 + (w & 1) * 4 + j) * 64 + lane) * 8];
#pragma unroll
            for (int i = 0; i < 4; i++)
#pragma unroll
                for (int j = 0; j < 4; j++)
                    acc[i][j] = __builtin_amdgcn_mfma_f32_16x16x32_bf16(a[i], b[j], acc[i][j], 0, 0, 0);
        }
    }

#pragma unroll
    for (int i = 0; i < 4; i++)
#pragma unroll
        for (int r = 0; r < 4; r++) {
            int m = m0 + wrow + i * 16 + quad * 4 + r;
#pragma unroll
            for (int j = 0; j < 4; j++)
                C[(size_t)m * 1024 + n0 + wcol + j * 16 + l15] = acc[i][j][r];
        }
}

// ---------------- causal flash attention: LDS-free, barrier-free ---------
// 1 wave per block, 32 q rows (2 frags of 16). grid (32 bh, 64 strips).
// QK^T via mfma_16x16x32_bf16 (K frags straight from global/L2).
// PV via mfma_16x16x16f16: exp(S) packs directly into the B-operand
// (n=lane&15=q, k=quad*4+j=key) -- no LDS round-trip, no barriers.
__global__ __launch_bounds__(64, 3) void flash_attn(
    const unsigned short* __restrict__ qb,
    const unsigned short* __restrict__ kb,
    const unsigned short* __restrict__ vt,   // f16 [B,H,hd,S]
    const float* __restrict__ fcos,
    const float* __restrict__ fsin,
    unsigned short* __restrict__ attnc)
{
    const int bh   = blockIdx.x;
    const int s    = 63 - blockIdx.y;        // strip: q rows [32s, 32s+32)
    const int b    = bh >> 4, h = bh & 15;
    const int lane = threadIdx.x;
    const int l15  = lane & 15;
    const int quad = lane >> 4;
    const size_t bhS = (size_t)bh * S_;

    // ---- Q fragments with fused rope + scale ----
    short8 qfrag[2][2];
    float mrow[2], lrow[2];
    const float SC = 0.125f * 1.44269504f;
#pragma unroll
    for (int f = 0; f < 2; f++) {
        int qrow = s * 32 + f * 16 + l15;
        const unsigned short* qp = qb + (bhS + qrow) * HD;
#pragma unroll
        for (int kh = 0; kh < 2; kh++) {
            uint4 u = *(const uint4*)(qp + kh * 32 + quad * 8);
            float4 c4 = *(const float4*)&fcos[qrow * 32 + kh * 16 + quad * 4];
            float4 s4 = *(const float4*)&fsin[qrow * 32 + kh * 16 + quad * 4];
            unsigned uu[4] = {u.x, u.y, u.z, u.w};
            const float* cc = (const float*)&c4;
            const float* ss = (const float*)&s4;
            unsigned o[4];
#pragma unroll
            for (int p = 0; p < 4; p++) {
                float r  = bf2f(uu[p] & 0xffffu), im = bf2f(uu[p] >> 16);
                float c  = cc[p] * SC, si = ss[p] * SC;
                o[p] = pack_bf16(im * c + r * si, r * c - im * si);
            }
            union { uint4 u4; short8 s8; } cvt;
            cvt.u4 = make_uint4(o[0], o[1], o[2], o[3]);
            qfrag[f][kh] = cvt.s8;
        }
        mrow[f] = -INFINITY;
        lrow[f] = 0.0f;
    }

    f32x4 O[2][4] = {};   // O^T: d = dt*16 + quad*4 + r, q = l15
    const int T  = s >> 1;          // full 64-key tiles
    const int P2 = s & 1;           // partial region has 2 + 2*P2 subtiles
    const unsigned short* kpbase = kb + (bhS + l15) * HD + quad * 8;
    const unsigned short* vrow   = vt + ((size_t)bh * HD + l15) * 2048;

    // ================= full tiles =================
    for (int jt = 0; jt < T; jt++) {
        const int j0 = jt * 64;
        const unsigned short* kp = kpbase + (size_t)j0 * HD;

        f32x4 Sacc[2][4];
#pragma unroll
        for (int sub = 0; sub < 4; sub++) {
            short8 kf0 = *(const short8*)(kp + (size_t)(sub * 16) * HD);
            short8 kf1 = *(const short8*)(kp + (size_t)(sub * 16) * HD + 32);
#pragma unroll
            for (int f = 0; f < 2; f++) {
                f32x4 sx = {};
                sx = __builtin_amdgcn_mfma_f32_16x16x32_bf16(kf0, qfrag[f][0], sx, 0, 0, 0);
                sx = __builtin_amdgcn_mfma_f32_16x16x32_bf16(kf1, qfrag[f][1], sx, 0, 0, 0);
                Sacc[f][sub] = sx;
            }
        }

        half4_ pf[2][4];
#pragma unroll
        for (int f = 0; f < 2; f++) {
            float tmax = -INFINITY;
#pragma unroll
            for (int sub = 0; sub < 4; sub++) {
                f32x4 sx = Sacc[f][sub];
                tmax = fmaxf(tmax, fmaxf(fmaxf(sx[0], sx[1]), fmaxf(sx[2], sx[3])));
            }
            tmax = fmaxf(tmax, __shfl_xor(tmax, 16, 64));
            tmax = fmaxf(tmax, __shfl_xor(tmax, 32, 64));
            float mnew = fmaxf(mrow[f], tmax);
            float ccr  = __builtin_amdgcn_exp2f(mrow[f] - mnew);
            float psum = 0.0f;
#pragma unroll
            for (int sub = 0; sub < 4; sub++) {
                f32x4 sx = Sacc[f][sub];
                float p0 = __builtin_amdgcn_exp2f(sx[0] - mnew);
                float p1 = __builtin_amdgcn_exp2f(sx[1] - mnew);
                float p2 = __builtin_amdgcn_exp2f(sx[2] - mnew);
                float p3 = __builtin_amdgcn_exp2f(sx[3] - mnew);
                psum += (p0 + p1) + (p2 + p3);
                union { pk16x2 h2[2]; half4_ h4; } u;
                u.h2[0] = __builtin_amdgcn_cvt_pkrtz(p0, p1);
                u.h2[1] = __builtin_amdgcn_cvt_pkrtz(p2, p3);
                pf[f][sub] = u.h4;
            }
            psum += __shfl_xor(psum, 16, 64);
            psum += __shfl_xor(psum, 32, 64);
            lrow[f] = lrow[f] * ccr + psum;
            mrow[f] = mnew;
#pragma unroll
            for (int dt = 0; dt < 4; dt++) {
                O[f][dt][0] *= ccr; O[f][dt][1] *= ccr;
                O[f][dt][2] *= ccr; O[f][dt][3] *= ccr;
            }
        }

#pragma unroll
        for (int sub = 0; sub < 4; sub++)
#pragma unroll
            for (int dt = 0; dt < 4; dt++) {
                half4_ vfr = *(const half4_*)(vrow + (size_t)(dt * 16) * 2048
                                              + j0 + sub * 16 + quad * 4);
#pragma unroll
                for (int f = 0; f < 2; f++)
                    O[f][dt] = __builtin_amdgcn_mfma_f32_16x16x16f16(vfr, pf[f][sub], O[f][dt], 0, 0, 0);
            }
    }

    // ================= partial region =================
    // keys [64T, 64T + 32 + 32*P2); lastsub(f) = 2*P2 + f; triangular at lastsub.
    {
        const int j0 = T * 64;
        const unsigned short* kp = kpbase + (size_t)j0 * HD;
        const int ls1 = 2 * P2 + 1;

        f32x4 Sacc[2][4];
#pragma unroll
        for (int sub = 0; sub < 4; sub++) {
            if (sub <= ls1) {
                short8 kf0 = *(const short8*)(kp + (size_t)(sub * 16) * HD);
                short8 kf1 = *(const short8*)(kp + (size_t)(sub * 16) * HD + 32);
#pragma unroll
                for (int f = 0; f < 2; f++) {
                    if (sub <= 2 * P2 + f) {
                        f32x4 sx = {};
                        sx = __builtin_amdgcn_mfma_f32_16x16x32_bf16(kf0, qfrag[f][0], sx, 0, 0, 0);
                        sx = __builtin_amdgcn_mfma_f32_16x16x32_bf16(kf1, qfrag[f][1], sx, 0, 0, 0);
                        Sacc[f][sub] = sx;
                    }
                }
            }
        }

        half4_ pf[2][4];
#pragma unroll
        for (int f = 0; f < 2; f++) {
            const int ls = 2 * P2 + f;
            float tmax = -INFINITY;
#pragma unroll
            for (int sub = 0; sub < 4; sub++) {
                if (sub <= ls) {
                    f32x4 sx = Sacc[f][sub];
                    if (sub == ls) {
#pragma unroll
                        for (int r = 0; r < 4; r++)
                            if (4 * quad + r > l15) sx[r] = -INFINITY;
                        Sacc[f][sub] = sx;
                    }
                    tmax = fmaxf(tmax, fmaxf(fmaxf(sx[0], sx[1]), fmaxf(sx[2], sx[3])));
                }
            }
            tmax = fmaxf(tmax, __shfl_xor(tmax, 16, 64));
            tmax = fmaxf(tmax, __shfl_xor(tmax, 32, 64));
            float mnew = fmaxf(mrow[f], tmax);
            float ccr  = __builtin_amdgcn_exp2f(mrow[f] - mnew);
            float psum = 0.0f;
#pragma unroll
            for (int sub = 0; sub < 4; sub++) {
                if (sub <= ls) {
                    f32x4 sx = Sacc[f][sub];
                    float p0 = __builtin_amdgcn_exp2f(sx[0] - mnew);
                    float p1 = __builtin_amdgcn_exp2f(sx[1] - mnew);
                    float p2 = __builtin_amdgcn_exp2f(sx[2] - mnew);
                    float p3 = __builtin_amdgcn_exp2f(sx[3] - mnew);
                    psum += (p0 + p1) + (p2 + p3);
                    union { pk16x2 h2[2]; half4_ h4; } u;
                    u.h2[0] = __builtin_amdgcn_cvt_pkrtz(p0, p1);
                    u.h2[1] = __builtin_amdgcn_cvt_pkrtz(p2, p3);
                    pf[f][sub] = u.h4;
                }
            }
            psum += __shfl_xor(psum, 16, 64);
            psum += __shfl_xor(psum, 32, 64);
            lrow[f] = lrow[f] * ccr + psum;
            mrow[f] = mnew;
#pragma unroll
            for (int dt = 0; dt < 4; dt++) {
                O[f][dt][0] *= ccr; O[f][dt][1] *= ccr;
                O[f][dt][2] *= ccr; O[f][dt][3] *= ccr;
            }
        }

#pragma unroll
        for (int sub = 0; sub < 4; sub++) {
            if (sub <= ls1) {
#pragma unroll
                for (int dt = 0; dt < 4; dt++) {
                    half4_ vfr = *(const half4_*)(vrow + (size_t)(dt * 16) * 2048
                                                  + j0 + sub * 16 + quad * 4);
#pragma unroll
                    for (int f = 0; f < 2; f++)
                        if (sub <= 2 * P2 + f)
                            O[f][dt] = __builtin_amdgcn_mfma_f32_16x16x16f16(vfr, pf[f][sub], O[f][dt], 0, 0, 0);
                }
            }
        }
    }

    // ---- epilogue ----
#pragma unroll
    for (int f = 0; f < 2; f++) {
        float inv = 1.0f / lrow[f];
        int qrow = s * 32 + f * 16 + l15;
        unsigned short* op = attnc + (((size_t)b * S_ + qrow) * H_ + h) * HD;
#pragma unroll
        for (int dt = 0; dt < 4; dt++)
#pragma unroll
            for (int r = 0; r < 4; r++)
                op[dt * 16 + quad * 4 + r] = f2bf(O[f][dt][r] * inv);
    }
}

// ---------------- launch ----------------
extern "C" void kernel_launch(void* const* d_in, const int* in_sizes, int n_in,
                              void* d_out, int out_size, void* d_ws, size_t ws_size,
                              hipStream_t stream) {
    const float* x    = (const float*)d_in[0];
    const float* fcos = (const float*)d_in[1];
    const float* fsin = (const float*)d_in[2];
    const float* Wq   = (const float*)d_in[3];
    const float* Wk   = (const float*)d_in[4];
    const float* Wv   = (const float*)d_in[5];
    const float* Wo   = (const float*)d_in[6];
    float* out = (float*)d_out;

    unsigned short* ws = (unsigned short*)d_ws;
    unsigned short* xbf = ws;
    unsigned short* wqb = xbf + 4096 * 1024;
    unsigned short* wkb = wqb + 1024 * 1024;
    unsigned short* wvb = wkb + 1024 * 1024;
    unsigned short* wob = wvb + 1024 * 1024;
    unsigned short* qb  = wob + 1024 * 1024;
    unsigned short* kb  = qb + 4096 * 1024;
    unsigned short* vt  = kb + 4096 * 1024;        // f16, transposed [B,H,hd,S]
    unsigned short* attnc = vt + 4096 * 1024;

    cvt_all<<<8192, 256, 0, stream>>>(x, Wq, Wk, Wv, Wo, xbf, wqb);

    qkv_gemm<<<dim3(32, 24), 256, 0, stream>>>(xbf, wqb, wkb, wvb, fcos, fsin, qb, kb, vt);

    flash_attn<<<dim3(32, 64), 64, 0, stream>>>(qb, kb, vt, fcos, fsin, attnc);

    out_gemm<<<dim3(32, 8), 256, 0, stream>>>(attnc, wob, out);
}

// Round 8
// 283.020 us; speedup vs baseline: 1.0824x; 1.0824x over previous
//
#include <hip/hip_runtime.h>
#include <hip/hip_bf16.h>
#include <cstdint>

typedef __attribute__((ext_vector_type(8))) short short8;
typedef __attribute__((ext_vector_type(4))) float f32x4;
typedef __attribute__((ext_vector_type(2))) __fp16 pk16x2;     // cvt_pkrtz native type
typedef __attribute__((ext_vector_type(4))) _Float16 half4_;

#define B_  2
#define S_  2048
#define D_  1024
#define H_  16
#define HD  64

static __device__ __forceinline__ float bf2f(unsigned int u16) {
    union { unsigned int i; float f; } v; v.i = u16 << 16; return v.f;
}
static __device__ __forceinline__ unsigned short f2bf(float f) {
    union { float f; unsigned int i; } v; v.f = f;
    unsigned int r = v.i + 0x7FFFu + ((v.i >> 16) & 1u);
    return (unsigned short)(r >> 16);
}
static __device__ __forceinline__ unsigned pack_bf16(float hi, float lo) {
    union { float f; unsigned u; } h, l;
    h.f = hi; l.f = lo;
    return __builtin_amdgcn_perm(h.u + 0x8000u, l.u + 0x8000u, 0x07060302);
}
static __device__ __forceinline__ void load_lds_16B(const unsigned short* g, unsigned short* l) {
    __builtin_amdgcn_global_load_lds(
        (const __attribute__((address_space(1))) unsigned int*)g,
        (__attribute__((address_space(3))) unsigned int*)l, 16, 0, 0);
}

// ---------------- fp32 -> bf16 conversion, x + all 4 weights -------------
__global__ void cvt_all(const float* __restrict__ x,
                        const float* __restrict__ w0, const float* __restrict__ w1,
                        const float* __restrict__ w2, const float* __restrict__ w3,
                        unsigned short* __restrict__ xbf,
                        unsigned short* __restrict__ wdst) {
    int bid = blockIdx.x;
    if (bid < 4096) {
        int i = bid * 256 + threadIdx.x;
        float4 f = ((const float4*)x)[i];
        uint2 o;
        o.x = (unsigned int)f2bf(f.x) | ((unsigned int)f2bf(f.y) << 16);
        o.y = (unsigned int)f2bf(f.z) | ((unsigned int)f2bf(f.w) << 16);
        ((uint2*)xbf)[i] = o;
    } else {
        int b2 = bid - 4096;
        int wsel = b2 >> 10;
        const float* s = wsel == 0 ? w0 : wsel == 1 ? w1 : wsel == 2 ? w2 : w3;
        int i = (b2 & 1023) * 256 + threadIdx.x;
        float4 f = ((const float4*)s)[i];
        uint2 o;
        o.x = (unsigned int)f2bf(f.x) | ((unsigned int)f2bf(f.y) << 16);
        o.y = (unsigned int)f2bf(f.z) | ((unsigned int)f2bf(f.w) << 16);
        ((uint2*)(wdst + (size_t)wsel * 1048576))[i] = o;
    }
}

// ---------------- fused QKV GEMM, 128x128 tile, BK=32 (round-3 proven) ---
// q written [B,H,S,hd] bf16; k written [B,H,S,hd] bf16 WITH ROPE APPLIED;
// v written TRANSPOSED f16 to vt [B,H,hd,S].
__global__ __launch_bounds__(256) void qkv_gemm(
    const unsigned short* __restrict__ xbf,
    const unsigned short* __restrict__ wq,
    const unsigned short* __restrict__ wk,
    const unsigned short* __restrict__ wv,
    const float* __restrict__ fcos,
    const float* __restrict__ fsin,
    unsigned short* __restrict__ qb,
    unsigned short* __restrict__ kb,
    unsigned short* __restrict__ vt)
{
    __shared__ unsigned short As[8 * 512];
    __shared__ unsigned short Bs[8 * 512];
    __shared__ unsigned short LT[64 * 136];      // V transpose buffer

    const int tid  = threadIdx.x;
    const int w    = tid >> 6, lane = tid & 63;
    const int l15  = lane & 15, quad = lane >> 4;
    const int wrow = (w >> 1) * 64, wcol = (w & 1) * 64;

    const int m0 = blockIdx.x * 128;
    const int nc = blockIdx.y * 128;
    const int sel = nc >> 10;
    const int n0 = nc & 1023;
    const unsigned short* __restrict__ W = sel == 0 ? wq : (sel == 1 ? wk : wv);

    const int slr = lane & 15, scg = (lane >> 4) * 8;
    const unsigned short* ga = xbf + (size_t)(m0 + slr) * 1024 + scg;
    const unsigned short* gb = W   + (size_t)(n0 + slr) * 1024 + scg;

    f32x4 acc[4][4] = {};

    for (int k0 = 0; k0 < 1024; k0 += 32) {
        __syncthreads();
        load_lds_16B(ga + (size_t)(w * 16) * 1024 + k0,        As + w * 512);
        load_lds_16B(ga + (size_t)(64 + w * 16) * 1024 + k0,   As + (w + 4) * 512);
        load_lds_16B(gb + (size_t)(w * 16) * 1024 + k0,        Bs + w * 512);
        load_lds_16B(gb + (size_t)(64 + w * 16) * 1024 + k0,   Bs + (w + 4) * 512);
        __syncthreads();

        short8 a[4], b[4];
#pragma unroll
        for (int i = 0; i < 4; i++)
            a[i] = *(const short8*)&As[(((w >> 1) * 4 + i) * 64 + lane) * 8];
#pragma unroll
        for (int j = 0; j < 4; j++)
            b[j] = *(const short8*)&Bs[(((w & 1) * 4 + j) * 64 + lane) * 8];
#pragma unroll
        for (int i = 0; i < 4; i++)
#pragma unroll
            for (int j = 0; j < 4; j++)
                acc[i][j] = __builtin_amdgcn_mfma_f32_16x16x32_bf16(a[i], b[j], acc[i][j], 0, 0, 0);
    }

    if (sel == 0) {
        // Q: plain scatter to [B,H,S,hd]
#pragma unroll
        for (int i = 0; i < 4; i++)
#pragma unroll
            for (int r = 0; r < 4; r++) {
                int m = m0 + wrow + i * 16 + quad * 4 + r;
                int bb = m >> 11, s = m & 2047;
#pragma unroll
                for (int j = 0; j < 4; j++) {
                    int n = n0 + wcol + j * 16 + l15;
                    int h = n >> 6, d = n & 63;
                    qb[(((size_t)(bb * H_ + h) * S_) + s) * HD + d] = f2bf(acc[i][j][r]);
                }
            }
    } else if (sel == 1) {
        // K: fused RoPE (pair exchange via shfl_xor lane^1), then scatter
#pragma unroll
        for (int i = 0; i < 4; i++)
#pragma unroll
            for (int r = 0; r < 4; r++) {
                int m = m0 + wrow + i * 16 + quad * 4 + r;
                int bb = m >> 11, s = m & 2047;
#pragma unroll
                for (int j = 0; j < 4; j++) {
                    int n = n0 + wcol + j * 16 + l15;
                    int h = n >> 6, d = n & 63, t = d >> 1;
                    float v = acc[i][j][r];
                    float o = __shfl_xor(v, 1, 64);
                    float c  = fcos[s * 32 + t];
                    float si = fsin[s * 32 + t];
                    float outv = (l15 & 1) ? (v * c + o * si) : (v * c - o * si);
                    kb[(((size_t)(bb * H_ + h) * S_) + s) * HD + d] = f2bf(outv);
                }
            }
    } else {
        // V: transpose via LDS, write f16 to vt[B,H,hd,S]
        const int bb = m0 >> 11, s0 = m0 & 2047;
#pragma unroll
        for (int nh = 0; nh < 2; nh++) {
            __syncthreads();
            if ((w & 1) == nh) {
#pragma unroll
                for (int i = 0; i < 4; i++)
#pragma unroll
                    for (int r = 0; r < 4; r++) {
                        int ml = wrow + i * 16 + quad * 4 + r;
#pragma unroll
                        for (int j = 0; j < 4; j++) {
                            union { _Float16 h; unsigned short u; } cv;
                            cv.h = (_Float16)acc[i][j][r];
                            LT[(j * 16 + l15) * 136 + ml] = cv.u;
                        }
                    }
            }
            __syncthreads();
            int dloc = tid >> 2, mseg = tid & 3;
            int h = (n0 + nh * 64) >> 6;
            unsigned short* dst = vt + (((size_t)bb * H_ + h) * HD + dloc) * 2048 + s0 + mseg * 32;
            uint2 r0 = *(const uint2*)&LT[dloc * 136 + mseg * 32];
            uint2 r1 = *(const uint2*)&LT[dloc * 136 + mseg * 32 + 4];
            uint2 r2 = *(const uint2*)&LT[dloc * 136 + mseg * 32 + 8];
            uint2 r3 = *(const uint2*)&LT[dloc * 136 + mseg * 32 + 12];
            uint2 r4 = *(const uint2*)&LT[dloc * 136 + mseg * 32 + 16];
            uint2 r5 = *(const uint2*)&LT[dloc * 136 + mseg * 32 + 20];
            uint2 r6 = *(const uint2*)&LT[dloc * 136 + mseg * 32 + 24];
            uint2 r7 = *(const uint2*)&LT[dloc * 136 + mseg * 32 + 28];
            ((uint4*)dst)[0] = make_uint4(r0.x, r0.y, r1.x, r1.y);
            ((uint4*)dst)[1] = make_uint4(r2.x, r2.y, r3.x, r3.y);
            ((uint4*)dst)[2] = make_uint4(r4.x, r4.y, r5.x, r5.y);
            ((uint4*)dst)[3] = make_uint4(r6.x, r6.y, r7.x, r7.y);
        }
    }
}

// ---------------- output GEMM, BK=32 -------------------------------------
__global__ __launch_bounds__(256) void out_gemm(
    const unsigned short* __restrict__ A,
    const unsigned short* __restrict__ Bt,
    float* __restrict__ C)
{
    __shared__ unsigned short As[8 * 512];
    __shared__ unsigned short Bs[8 * 512];

    const int tid  = threadIdx.x;
    const int w    = tid >> 6, lane = tid & 63;
    const int l15  = lane & 15, quad = lane >> 4;
    const int wrow = (w >> 1) * 64, wcol = (w & 1) * 64;

    const int m0 = blockIdx.x * 128;
    const int n0 = blockIdx.y * 128;

    const int slr = lane & 15, scg = (lane >> 4) * 8;
    const unsigned short* ga = A  + (size_t)(m0 + slr) * 1024 + scg;
    const unsigned short* gb = Bt + (size_t)(n0 + slr) * 1024 + scg;

    f32x4 acc[4][4] = {};

    for (int k0 = 0; k0 < 1024; k0 += 32) {
        __syncthreads();
        load_lds_16B(ga + (size_t)(w * 16) * 1024 + k0,        As + w * 512);
        load_lds_16B(ga + (size_t)(64 + w * 16) * 1024 + k0,   As + (w + 4) * 512);
        load_lds_16B(gb + (size_t)(w * 16) * 1024 + k0,        Bs + w * 512);
        load_lds_16B(gb + (size_t)(64 + w * 16) * 1024 + k0,   Bs + (w + 4) * 512);
        __syncthreads();

        short8 a[4], b[4];
#pragma unroll
        for (int i = 0; i < 4; i++)
            a[i] = *(const short8*)&As[(((w >> 1) * 4 + i) * 64 + lane) * 8];
#pragma unroll
        for (int j = 0; j < 4; j++)
            b[j] = *(const short8*)&Bs[(((w & 1) * 4 + j) * 64 + lane) * 8];
#pragma unroll
        for (int i = 0; i < 4; i++)
#pragma unroll
            for (int j = 0; j < 4; j++)
                acc[i][j] = __builtin_amdgcn_mfma_f32_16x16x32_bf16(a[i], b[j], acc[i][j], 0, 0, 0);
    }

#pragma unroll
    for (int i = 0; i < 4; i++)
#pragma unroll
        for (int r = 0; r < 4; r++) {
            int m = m0 + wrow + i * 16 + quad * 4 + r;
#pragma unroll
            for (int j = 0; j < 4; j++)
                C[(size_t)m * 1024 + n0 + wcol + j * 16 + l15] = acc[i][j][r];
        }
}

// ---------------- causal flash attention: LDS-free + K reg-prefetch ------
// 1 wave per block, 32 q rows (2 frags of 16). grid (32 bh, 64 strips).
// K double-buffered in registers one tile ahead (consumed immediately by
// QK MFMA); V issued at tile start, consumed after QK+softmax (~300 cyc).
// Issue order per tile: [V this tile][K next tile] so PV's wait leaves the
// K prefetch in flight. PV via mfma_16x16x16f16 (P packs straight into
// the B-operand). No LDS, no barriers.
__global__ __launch_bounds__(64, 2) void flash_attn(
    const unsigned short* __restrict__ qb,
    const unsigned short* __restrict__ kb,
    const unsigned short* __restrict__ vt,   // f16 [B,H,hd,S]
    const float* __restrict__ fcos,
    const float* __restrict__ fsin,
    unsigned short* __restrict__ attnc)
{
    const int bh   = blockIdx.x;
    const int s    = 63 - blockIdx.y;        // strip: q rows [32s, 32s+32)
    const int b    = bh >> 4, h = bh & 15;
    const int lane = threadIdx.x;
    const int l15  = lane & 15;
    const int quad = lane >> 4;
    const size_t bhS = (size_t)bh * S_;

    // ---- Q fragments with fused rope + scale ----
    short8 qfrag[2][2];
    float mrow[2], lrow[2];
    const float SC = 0.125f * 1.44269504f;
#pragma unroll
    for (int f = 0; f < 2; f++) {
        int qrow = s * 32 + f * 16 + l15;
        const unsigned short* qp = qb + (bhS + qrow) * HD;
#pragma unroll
        for (int kh = 0; kh < 2; kh++) {
            uint4 u = *(const uint4*)(qp + kh * 32 + quad * 8);
            float4 c4 = *(const float4*)&fcos[qrow * 32 + kh * 16 + quad * 4];
            float4 s4 = *(const float4*)&fsin[qrow * 32 + kh * 16 + quad * 4];
            unsigned uu[4] = {u.x, u.y, u.z, u.w};
            const float* cc = (const float*)&c4;
            const float* ss = (const float*)&s4;
            unsigned o[4];
#pragma unroll
            for (int p = 0; p < 4; p++) {
                float r  = bf2f(uu[p] & 0xffffu), im = bf2f(uu[p] >> 16);
                float c  = cc[p] * SC, si = ss[p] * SC;
                o[p] = pack_bf16(im * c + r * si, r * c - im * si);
            }
            union { uint4 u4; short8 s8; } cvt;
            cvt.u4 = make_uint4(o[0], o[1], o[2], o[3]);
            qfrag[f][kh] = cvt.s8;
        }
        mrow[f] = -INFINITY;
        lrow[f] = 0.0f;
    }

    f32x4 O[2][4] = {};   // O^T: d = dt*16 + quad*4 + r, q = l15
    const int T  = s >> 1;          // full 64-key tiles
    const int P2 = s & 1;           // partial region has 2 + 2*P2 subtiles
    const unsigned short* kpbase = kb + (bhS + l15) * HD + quad * 8;
    const unsigned short* vrow   = vt + ((size_t)bh * HD + l15) * 2048;

    // prefetch K tile 0
    short8 kn[4][2];
    if (T > 0) {
#pragma unroll
        for (int sub = 0; sub < 4; sub++) {
            kn[sub][0] = *(const short8*)(kpbase + (size_t)(sub * 16) * HD);
            kn[sub][1] = *(const short8*)(kpbase + (size_t)(sub * 16) * HD + 32);
        }
    }

    // ================= full tiles =================
    for (int jt = 0; jt < T; jt++) {
        const int j0 = jt * 64;

        // take current K (renames, no copies after regalloc)
        short8 kc[4][2];
#pragma unroll
        for (int sub = 0; sub < 4; sub++) {
            kc[sub][0] = kn[sub][0];
            kc[sub][1] = kn[sub][1];
        }

        // issue V loads for THIS tile (consumed late)
        half4_ vc[4][4];
#pragma unroll
        for (int sub = 0; sub < 4; sub++)
#pragma unroll
            for (int dt = 0; dt < 4; dt++)
                vc[sub][dt] = *(const half4_*)(vrow + (size_t)(dt * 16) * 2048
                                               + j0 + sub * 16 + quad * 4);

        // prefetch NEXT tile's K (issued after V: PV's wait keeps these in flight)
        if (jt + 1 < T) {
            const unsigned short* kp2 = kpbase + (size_t)(j0 + 64) * HD;
#pragma unroll
            for (int sub = 0; sub < 4; sub++) {
                kn[sub][0] = *(const short8*)(kp2 + (size_t)(sub * 16) * HD);
                kn[sub][1] = *(const short8*)(kp2 + (size_t)(sub * 16) * HD + 32);
            }
        }

        // ---- QK on current K (already in registers) ----
        f32x4 Sacc[2][4];
#pragma unroll
        for (int sub = 0; sub < 4; sub++)
#pragma unroll
            for (int f = 0; f < 2; f++) {
                f32x4 sx = {};
                sx = __builtin_amdgcn_mfma_f32_16x16x32_bf16(kc[sub][0], qfrag[f][0], sx, 0, 0, 0);
                sx = __builtin_amdgcn_mfma_f32_16x16x32_bf16(kc[sub][1], qfrag[f][1], sx, 0, 0, 0);
                Sacc[f][sub] = sx;
            }

        // ---- softmax + PV, per fragment ----
#pragma unroll
        for (int f = 0; f < 2; f++) {
            float tmax = -INFINITY;
#pragma unroll
            for (int sub = 0; sub < 4; sub++) {
                f32x4 sx = Sacc[f][sub];
                tmax = fmaxf(tmax, fmaxf(fmaxf(sx[0], sx[1]), fmaxf(sx[2], sx[3])));
            }
            tmax = fmaxf(tmax, __shfl_xor(tmax, 16, 64));
            tmax = fmaxf(tmax, __shfl_xor(tmax, 32, 64));
            float mnew = fmaxf(mrow[f], tmax);
            float ccr  = __builtin_amdgcn_exp2f(mrow[f] - mnew);
            float psum = 0.0f;
            half4_ pf[4];
#pragma unroll
            for (int sub = 0; sub < 4; sub++) {
                f32x4 sx = Sacc[f][sub];
                float p0 = __builtin_amdgcn_exp2f(sx[0] - mnew);
                float p1 = __builtin_amdgcn_exp2f(sx[1] - mnew);
                float p2 = __builtin_amdgcn_exp2f(sx[2] - mnew);
                float p3 = __builtin_amdgcn_exp2f(sx[3] - mnew);
                psum += (p0 + p1) + (p2 + p3);
                union { pk16x2 h2[2]; half4_ h4; } u;
                u.h2[0] = __builtin_amdgcn_cvt_pkrtz(p0, p1);
                u.h2[1] = __builtin_amdgcn_cvt_pkrtz(p2, p3);
                pf[sub] = u.h4;
            }
            psum += __shfl_xor(psum, 16, 64);
            psum += __shfl_xor(psum, 32, 64);
            lrow[f] = lrow[f] * ccr + psum;
            mrow[f] = mnew;
#pragma unroll
            for (int dt = 0; dt < 4; dt++) {
                O[f][dt][0] *= ccr; O[f][dt][1] *= ccr;
                O[f][dt][2] *= ccr; O[f][dt][3] *= ccr;
            }
#pragma unroll
            for (int sub = 0; sub < 4; sub++)
#pragma unroll
                for (int dt = 0; dt < 4; dt++)
                    O[f][dt] = __builtin_amdgcn_mfma_f32_16x16x16f16(vc[sub][dt], pf[sub], O[f][dt], 0, 0, 0);
        }
    }

    // ================= partial region =================
    // keys [64T, 64T + 32 + 32*P2); lastsub(f) = 2*P2 + f; triangular at lastsub.
    {
        const int j0 = T * 64;
        const unsigned short* kp = kpbase + (size_t)j0 * HD;
        const int ls1 = 2 * P2 + 1;

        f32x4 Sacc[2][4];
#pragma unroll
        for (int sub = 0; sub < 4; sub++) {
            if (sub <= ls1) {
                short8 kf0 = *(const short8*)(kp + (size_t)(sub * 16) * HD);
                short8 kf1 = *(const short8*)(kp + (size_t)(sub * 16) * HD + 32);
#pragma unroll
                for (int f = 0; f < 2; f++) {
                    if (sub <= 2 * P2 + f) {
                        f32x4 sx = {};
                        sx = __builtin_amdgcn_mfma_f32_16x16x32_bf16(kf0, qfrag[f][0], sx, 0, 0, 0);
                        sx = __builtin_amdgcn_mfma_f32_16x16x32_bf16(kf1, qfrag[f][1], sx, 0, 0, 0);
                        Sacc[f][sub] = sx;
                    }
                }
            }
        }

        half4_ pf[2][4];
#pragma unroll
        for (int f = 0; f < 2; f++) {
            const int ls = 2 * P2 + f;
            float tmax = -INFINITY;
#pragma unroll
            for (int sub = 0; sub < 4; sub++) {
                if (sub <= ls) {
                    f32x4 sx = Sacc[f][sub];
                    if (sub == ls) {
#pragma unroll
                        for (int r = 0; r < 4; r++)
                            if (4 * quad + r > l15) sx[r] = -INFINITY;
                        Sacc[f][sub] = sx;
                    }
                    tmax = fmaxf(tmax, fmaxf(fmaxf(sx[0], sx[1]), fmaxf(sx[2], sx[3])));
                }
            }
            tmax = fmaxf(tmax, __shfl_xor(tmax, 16, 64));
            tmax = fmaxf(tmax, __shfl_xor(tmax, 32, 64));
            float mnew = fmaxf(mrow[f], tmax);
            float ccr  = __builtin_amdgcn_exp2f(mrow[f] - mnew);
            float psum = 0.0f;
#pragma unroll
            for (int sub = 0; sub < 4; sub++) {
                if (sub <= ls) {
                    f32x4 sx = Sacc[f][sub];
                    float p0 = __builtin_amdgcn_exp2f(sx[0] - mnew);
                    float p1 = __builtin_amdgcn_exp2f(sx[1] - mnew);
                    float p2 = __builtin_amdgcn_exp2f(sx[2] - mnew);
                    float p3 = __builtin_amdgcn_exp2f(sx[3] - mnew);
                    psum += (p0 + p1) + (p2 + p3);
                    union { pk16x2 h2[2]; half4_ h4; } u;
                    u.h2[0] = __builtin_amdgcn_cvt_pkrtz(p0, p1);
                    u.h2[1] = __builtin_amdgcn_cvt_pkrtz(p2, p3);
                    pf[f][sub] = u.h4;
                }
            }
            psum += __shfl_xor(psum, 16, 64);
            psum += __shfl_xor(psum, 32, 64);
            lrow[f] = lrow[f] * ccr + psum;
            mrow[f] = mnew;
#pragma unroll
            for (int dt = 0; dt < 4; dt++) {
                O[f][dt][0] *= ccr; O[f][dt][1] *= ccr;
                O[f][dt][2] *= ccr; O[f][dt][3] *= ccr;
            }
        }

#pragma unroll
        for (int sub = 0; sub < 4; sub++) {
            if (sub <= ls1) {
#pragma unroll
                for (int dt = 0; dt < 4; dt++) {
                    half4_ vfr = *(const half4_*)(vrow + (size_t)(dt * 16) * 2048
                                                  + j0 + sub * 16 + quad * 4);
#pragma unroll
                    for (int f = 0; f < 2; f++)
                        if (sub <= 2 * P2 + f)
                            O[f][dt] = __builtin_amdgcn_mfma_f32_16x16x16f16(vfr, pf[f][sub], O[f][dt], 0, 0, 0);
                }
            }
        }
    }

    // ---- epilogue ----
#pragma unroll
    for (int f = 0; f < 2; f++) {
        float inv = 1.0f / lrow[f];
        int qrow = s * 32 + f * 16 + l15;
        unsigned short* op = attnc + (((size_t)b * S_ + qrow) * H_ + h) * HD;
#pragma unroll
        for (int dt = 0; dt < 4; dt++)
#pragma unroll
            for (int r = 0; r < 4; r++)
                op[dt * 16 + quad * 4 + r] = f2bf(O[f][dt][r] * inv);
    }
}

// ---------------- launch ----------------
extern "C" void kernel_launch(void* const* d_in, const int* in_sizes, int n_in,
                              void* d_out, int out_size, void* d_ws, size_t ws_size,
                              hipStream_t stream) {
    const float* x    = (const float*)d_in[0];
    const float* fcos = (const float*)d_in[1];
    const float* fsin = (const float*)d_in[2];
    const float* Wq   = (const float*)d_in[3];
    const float* Wk   = (const float*)d_in[4];
    const float* Wv   = (const float*)d_in[5];
    const float* Wo   = (const float*)d_in[6];
    float* out = (float*)d_out;

    unsigned short* ws = (unsigned short*)d_ws;
    unsigned short* xbf = ws;
    unsigned short* wqb = xbf + 4096 * 1024;
    unsigned short* wkb = wqb + 1024 * 1024;
    unsigned short* wvb = wkb + 1024 * 1024;
    unsigned short* wob = wvb + 1024 * 1024;
    unsigned short* qb  = wob + 1024 * 1024;
    unsigned short* kb  = qb + 4096 * 1024;
    unsigned short* vt  = kb + 4096 * 1024;        // f16, transposed [B,H,hd,S]
    unsigned short* attnc = vt + 4096 * 1024;

    cvt_all<<<8192, 256, 0, stream>>>(x, Wq, Wk, Wv, Wo, xbf, wqb);

    qkv_gemm<<<dim3(32, 24), 256, 0, stream>>>(xbf, wqb, wkb, wvb, fcos, fsin, qb, kb, vt);

    flash_attn<<<dim3(32, 64), 64, 0, stream>>>(qb, kb, vt, fcos, fsin, attnc);

    out_gemm<<<dim3(32, 8), 256, 0, stream>>>(attnc, wob, out);
}